// Round 1
// baseline (704.104 us; speedup 1.0000x reference)
//
#include <hip/hip_runtime.h>
#include <math.h>

// Problem constants (from reference): B=16, N=4096, H=2048, fp32.
constexpr int B = 16;
constexpr int N = 4096;
constexpr int H = 2048;

constexpr int BLOCKS_PER_BATCH = 32;                     // 512 blocks total
constexpr int WAVES_PER_BLOCK  = 4;                      // 256 threads
constexpr int WAVES_PER_BATCH  = BLOCKS_PER_BATCH * WAVES_PER_BLOCK; // 128
constexpr int ROWS_PER_WAVE    = N / WAVES_PER_BATCH;    // 32
constexpr int F4_PER_ROW       = H / 4;                  // 512 float4 per row
constexpr int F4_PER_LANE      = F4_PER_ROW / 64;        // 8 float4 per lane

// 1/sqrt(2048)
__device__ __constant__ float kInvScale = 0.022097086912079608f;

// Pass 1: one wave = 32 rows, online softmax, row stays in registers between
// QK^T dot and PV accumulate -> outputs[] is read from HBM exactly once.
__global__ __launch_bounds__(256, 2) void attn_pass1(
    const float* __restrict__ outs,      // [B, N, H]
    const float* __restrict__ last_h,    // [B, H]
    float* __restrict__ ws_logits,       // [B, N]
    float* __restrict__ ws_m,            // [B, WAVES_PER_BATCH]
    float* __restrict__ ws_l,            // [B, WAVES_PER_BATCH]
    float* __restrict__ ws_ctx)          // [B, WAVES_PER_BATCH, H]
{
    const int b    = blockIdx.x / BLOCKS_PER_BATCH;
    const int blk  = blockIdx.x % BLOCKS_PER_BATCH;
    const int wave = threadIdx.x >> 6;
    const int lane = threadIdx.x & 63;
    const int wid  = blk * WAVES_PER_BLOCK + wave;  // 0..127 within batch
    const int row0 = wid * ROWS_PER_WAVE;

    // q fragment: lane holds float4s {lane + 64*j}
    const float4* q4 = reinterpret_cast<const float4*>(last_h + (size_t)b * H);
    float4 q[F4_PER_LANE];
#pragma unroll
    for (int j = 0; j < F4_PER_LANE; ++j) q[j] = q4[lane + 64 * j];

    float4 ctx[F4_PER_LANE];
#pragma unroll
    for (int j = 0; j < F4_PER_LANE; ++j) ctx[j] = make_float4(0.f, 0.f, 0.f, 0.f);
    float m = -INFINITY;
    float l = 0.f;

    const float4* krow = reinterpret_cast<const float4*>(outs) +
                         ((size_t)b * N + row0) * F4_PER_ROW;

    for (int r = 0; r < ROWS_PER_WAVE; ++r) {
        float4 k[F4_PER_LANE];
#pragma unroll
        for (int j = 0; j < F4_PER_LANE; ++j) k[j] = krow[lane + 64 * j];
        krow += F4_PER_ROW;

        float s = 0.f;
#pragma unroll
        for (int j = 0; j < F4_PER_LANE; ++j)
            s += k[j].x * q[j].x + k[j].y * q[j].y + k[j].z * q[j].z + k[j].w * q[j].w;
        // wave-64 butterfly reduce; all lanes end with full dot
#pragma unroll
        for (int off = 32; off > 0; off >>= 1) s += __shfl_xor(s, off, 64);
        s *= kInvScale;

        if (lane == 0) ws_logits[(size_t)b * N + row0 + r] = s;

        if (s > m) {                    // wave-uniform branch, rare (~log rows)
            const float corr = __expf(m - s);   // m==-inf -> 0 (first row ok)
            l *= corr;
#pragma unroll
            for (int j = 0; j < F4_PER_LANE; ++j) {
                ctx[j].x *= corr; ctx[j].y *= corr;
                ctx[j].z *= corr; ctx[j].w *= corr;
            }
            m = s;
        }
        const float w = __expf(s - m);
        l += w;
#pragma unroll
        for (int j = 0; j < F4_PER_LANE; ++j) {
            ctx[j].x += w * k[j].x; ctx[j].y += w * k[j].y;
            ctx[j].z += w * k[j].z; ctx[j].w += w * k[j].w;
        }
    }

    const int gw = b * WAVES_PER_BATCH + wid;
    if (lane == 0) { ws_m[gw] = m; ws_l[gw] = l; }
    float4* cdst = reinterpret_cast<float4*>(ws_ctx) + (size_t)gw * F4_PER_ROW;
#pragma unroll
    for (int j = 0; j < F4_PER_LANE; ++j) cdst[lane + 64 * j] = ctx[j];
}

// Pass 2: per batch, combine 128 wave partials -> global M, L, ctx; write attn.
__global__ __launch_bounds__(256) void attn_pass2(
    const float* __restrict__ ws_logits,
    const float* __restrict__ ws_m,
    const float* __restrict__ ws_l,
    const float* __restrict__ ws_ctx,
    float* __restrict__ out_ctx,         // [B, H]
    float* __restrict__ out_attn)        // [B, N]
{
    __shared__ float lm[WAVES_PER_BATCH];
    __shared__ float ll[WAVES_PER_BATCH];
    __shared__ float lscale[WAVES_PER_BATCH];

    const int b   = blockIdx.x;
    const int tid = threadIdx.x;

    if (tid < WAVES_PER_BATCH) {
        lm[tid] = ws_m[b * WAVES_PER_BATCH + tid];
        ll[tid] = ws_l[b * WAVES_PER_BATCH + tid];
    }
    __syncthreads();

    float M = -INFINITY;
    for (int w = 0; w < WAVES_PER_BATCH; ++w) M = fmaxf(M, lm[w]);
    if (tid < WAVES_PER_BATCH) lscale[tid] = __expf(lm[tid] - M);
    __syncthreads();

    float L = 0.f;
    for (int w = 0; w < WAVES_PER_BATCH; ++w) L += lscale[w] * ll[w];
    const float invL = 1.f / L;

    // ctx combine: coalesced over float4 index
    const float4* c4 = reinterpret_cast<const float4*>(ws_ctx) +
                       (size_t)b * WAVES_PER_BATCH * F4_PER_ROW;
    float4* o4 = reinterpret_cast<float4*>(out_ctx) + (size_t)b * F4_PER_ROW;
    for (int f = tid; f < F4_PER_ROW; f += 256) {
        float4 acc = make_float4(0.f, 0.f, 0.f, 0.f);
        for (int w = 0; w < WAVES_PER_BATCH; ++w) {
            const float sc = lscale[w];
            const float4 v = c4[(size_t)w * F4_PER_ROW + f];
            acc.x += sc * v.x; acc.y += sc * v.y;
            acc.z += sc * v.z; acc.w += sc * v.w;
        }
        o4[f] = make_float4(acc.x * invL, acc.y * invL, acc.z * invL, acc.w * invL);
    }

    // attn = exp(logit - M) / L
    for (int n = tid; n < N; n += 256) {
        out_attn[(size_t)b * N + n] =
            __expf(ws_logits[(size_t)b * N + n] - M) * invL;
    }
}

extern "C" void kernel_launch(void* const* d_in, const int* in_sizes, int n_in,
                              void* d_out, int out_size, void* d_ws, size_t ws_size,
                              hipStream_t stream) {
    const float* outs   = (const float*)d_in[0];   // [B, N, H]
    const float* last_h = (const float*)d_in[1];   // [B, H]

    float* out_ctx  = (float*)d_out;               // [B, H]
    float* out_attn = (float*)d_out + (size_t)B * H; // [B, N]

    float* ws        = (float*)d_ws;
    float* ws_logits = ws;                                   // B*N
    float* ws_m      = ws_logits + (size_t)B * N;            // B*128
    float* ws_l      = ws_m + (size_t)B * WAVES_PER_BATCH;   // B*128
    float* ws_ctx    = ws_l + (size_t)B * WAVES_PER_BATCH;   // B*128*H (16 MiB)

    attn_pass1<<<B * BLOCKS_PER_BATCH, 256, 0, stream>>>(
        outs, last_h, ws_logits, ws_m, ws_l, ws_ctx);
    attn_pass2<<<B, 256, 0, stream>>>(
        ws_logits, ws_m, ws_l, ws_ctx, out_ctx, out_attn);
}